// Round 1
// baseline (819.374 us; speedup 1.0000x reference)
//
#include <hip/hip_runtime.h>
#include <hip/hip_bf16.h>

#define BB 32
#define CC 256
#define HH 56
#define WW 56
#define OO 512
#define CKK 2304

// padded x, NHWC bf16: [b][pix = y*58 + x][c], y,x in [0,58)
#define XR 58
#define XC 58
#define XPIX (XR * XC)        // 3364

// GEMM tiling: M-tile 256 (o), N-tile 112 = 4 y-rows x 28 x-cols
#define NY 4
#define NX 28
#define NTILE 112
#define TPC 30                // tile pixel cols (NX+2)
#define TPIX 180              // 6 rows * 30 cols
#define BUFB 16384            // LDS buffer stride (bytes); used 11,520

typedef __bf16 bf16x8 __attribute__((ext_vector_type(8)));
typedef float  f32x4  __attribute__((ext_vector_type(4)));

#define WT_OFF 4096
#define XP_OFF (WT_OFF + (size_t)OO * CKK * 2)   // 2.36 MB of weights

// ---------------------------------------------------------------------------
// Detect 1-byte vs 4-byte bools (u32 words > 1 => byte bools).
// ---------------------------------------------------------------------------
__global__ void detect_bool_width(const unsigned int* __restrict__ pos,
                                  unsigned int* __restrict__ flag) {
    unsigned int v = 0;
    for (int i = threadIdx.x; i < 16384; i += 256) v |= pos[i];
    __shared__ unsigned int red;
    if (threadIdx.x == 0) red = 0u;
    __syncthreads();
    if (v > 1u) atomicOr(&red, 1u);
    __syncthreads();
    if (threadIdx.x == 0) *flag = red;
}

// ---------------------------------------------------------------------------
// Decode ternary weights to bf16, transposed to w[o][k'] with
// k' = (c>>5)*288 + (kh*3+kw)*32 + (c&31)  (c-chunk-major, khw, c-in-chunk).
// ---------------------------------------------------------------------------
__global__ __launch_bounds__(256) void decode_w(
    const void* __restrict__ posv, const void* __restrict__ negv,
    const unsigned int* __restrict__ flag,
    unsigned short* __restrict__ wt) {
    __shared__ unsigned short lds[64][65];
    int blk = blockIdx.x;
    int ot  = blk & 7;
    int khw = (blk >> 3) % 9;
    int ct  = blk / 72;
    int o0 = ot * 64, c0 = ct * 64;
    int t = threadIdx.x;
    int o_l = t & 63, row4 = t >> 6;
    bool bytes = (*flag != 0u);
#pragma unroll
    for (int r = 0; r < 16; ++r) {
        int c_l = row4 + r * 4;
        long k = (long)(c0 + c_l) * 9 + khw;     // input k = c*9 + kh*3 + kw
        long idx = k * OO + o0 + o_l;
        int p, q;
        if (bytes) { p = ((const unsigned char*)posv)[idx];
                     q = ((const unsigned char*)negv)[idx]; }
        else       { p = ((const int*)posv)[idx];
                     q = ((const int*)negv)[idx]; }
        lds[c_l][o_l] = p ? 0x3F80u : (q ? 0xBF80u : 0u);
    }
    __syncthreads();
#pragma unroll
    for (int r = 0; r < 16; ++r) {
        int o_r = row4 + r * 4;
        int c = c0 + (t & 63);
        wt[(size_t)(o0 + o_r) * CKK + (c >> 5) * 288 + khw * 32 + (c & 31)] =
            lds[t & 63][o_r];
    }
}

// ---------------------------------------------------------------------------
// Pad + convert + transpose x to NHWC bf16: xp[b][y*58+x][c].
// One block per (b, y) output row; LDS transpose per 64-c chunk.
// ---------------------------------------------------------------------------
__global__ __launch_bounds__(256) void pad_x(const float* __restrict__ x,
                                             unsigned short* __restrict__ xp) {
    int blk = blockIdx.x;                 // 32*58
    int b = blk / XR, y = blk - b * XR;
    int t = threadIdx.x;
    unsigned short* rowp = xp + ((size_t)b * XPIX + (size_t)y * XC) * CC;
    if (y == 0 || y == XR - 1) {
        uint4 z = {0, 0, 0, 0};
        for (int i = t; i < XC * CC / 8; i += 256) ((uint4*)rowp)[i] = z;
        return;
    }
    __shared__ float lds[WW][65];
    for (int cb = 0; cb < 4; ++cb) {
        if (cb) __syncthreads();
#pragma unroll
        for (int i = 0; i < 14; ++i) {    // 3584 = 64 c * 56 x
            int idx = i * 256 + t;
            int cl = idx / WW, xx = idx - cl * WW;
            lds[xx][cl] =
                x[(((size_t)b * CC + cb * 64 + cl) * HH + (y - 1)) * WW + xx];
        }
        __syncthreads();
#pragma unroll
        for (int i = 0; i < 15; ++i) {    // 3712 = 58 x * 64 c
            int idx = i * 256 + t;
            if (idx < XC * 64) {
                int xx = idx >> 6, cl = idx & 63;
                float v = (xx == 0 || xx == XC - 1) ? 0.f : lds[xx - 1][cl];
                __hip_bfloat16 h = __float2bfloat16(v);
                rowp[(size_t)xx * CC + cb * 64 + cl] = *(unsigned short*)&h;
            }
        }
    }
}

// ---------------------------------------------------------------------------
// Implicit-GEMM conv, bf16 MFMA, c-chunk-outer K-loop.
//   Per chunk: stage 180 pix x 32 c tile via global_load_lds (double-buffered),
//   then 9 khw K-steps x 28 MFMAs per wave from LDS. 1 barrier / chunk.
// Grid 1792 = 896 n-blocks x 2 m-blocks (m swizzled onto same XCD).
//
// LDS B-tile is XOR-swizzled to kill the 4-way ds_read_b128 bank conflict:
//   16-B slot for (pixel p, channel-quad q) lives at p*4 + (q ^ ((p>>1)&3)).
//   global_load_lds writes linearly, so the *global source* is pre-swizzled
//   (lane fetching slot p*4+q' reads quad q'^((p>>1)&3)); the read side
//   applies the same XOR. 8 consecutive pixels -> 8 distinct bank slots.
// ---------------------------------------------------------------------------
__global__ __launch_bounds__(256, 2) void conv_mfma(
    const unsigned short* __restrict__ xp,
    const unsigned short* __restrict__ wt,
    float* __restrict__ out) {
    __shared__ __align__(1024) unsigned short Bs[2 * BUFB / 2];

    int t = threadIdx.x;
    int w = t >> 6, lane = t & 63, lm = lane & 15, lq = lane >> 4;

    int bx = blockIdx.x;
    int mb = (bx >> 3) & 1;                       // m innermost on same XCD
    int gn = ((bx >> 4) << 3) | (bx & 7);         // 0..895
    int b = gn / 28;
    int rem = gn - b * 28;
    int y0 = (rem >> 1) << 2;                     // 0..52
    int x0 = (rem & 1) * NX;                      // 0 or 28

    // per-nt pixel base within the tile (kh=kw=0 position), lane lm = n
    int pb[7];
#pragma unroll
    for (int nt = 0; nt < 7; ++nt) {
        int n = nt * 16 + lm;
        int ny = n / NX, nx = n - (n / NX) * NX;
        pb[nt] = ny * TPC + nx;
    }

    // Staging: 720 16-B units; 3 segments/wave, u = (w*3+i)*64 + lane.
    // Unit u = pix*4 + q writes LDS linearly; fetch quad q ^ ((pix>>1)&3)
    // from global so the swizzled read below finds its channels.
    const unsigned short* gsrc[3];
    int useg[3];
#pragma unroll
    for (int i = 0; i < 3; ++i) {
        int u = (w * 3 + i) * 64 + lane;
        useg[i] = u;
        int pix = u >> 2, q = u & 3;
        int qg = q ^ ((pix >> 1) & 3);
        int py = pix / TPC, px = pix - py * TPC;
        gsrc[i] = xp + ((size_t)b * XPIX + (y0 + py) * XC + (x0 + px)) * CC +
                  qg * 8;
    }
    int ldsseg = (w * 3) * 1024;

    const unsigned short* aptr[4];
#pragma unroll
    for (int mt = 0; mt < 4; ++mt)
        aptr[mt] = wt + (size_t)(mb * 256 + w * 64 + mt * 16 + lm) * CKK + lq * 8;

    f32x4 acc[4][7];
#pragma unroll
    for (int i = 0; i < 4; ++i)
#pragma unroll
        for (int j = 0; j < 7; ++j) acc[i][j] = (f32x4){0.f, 0.f, 0.f, 0.f};

    bf16x8 af[12];

#define STAGE(CHOFF, POFS)                                                     \
    {                                                                          \
        _Pragma("unroll") for (int i = 0; i < 3; ++i) {                        \
            if (useg[i] < TPIX * 4)                                            \
                __builtin_amdgcn_global_load_lds(                              \
                    (const __attribute__((address_space(1))) void*)(gsrc[i] +  \
                                                                    (CHOFF)),  \
                    (__attribute__((address_space(3))) void*)((char*)Bs +      \
                                                              (POFS) + ldsseg +\
                                                              i * 1024),       \
                    16, 0, 0);                                                 \
        }                                                                      \
    }

#define LOADA(CHEL, G)                                                         \
    {                                                                          \
        _Pragma("unroll") for (int j = 0; j < 3; ++j)                          \
            _Pragma("unroll") for (int mt = 0; mt < 4; ++mt)                   \
                af[j * 4 + mt] = *(const bf16x8*)(aptr[mt] + (CHEL) +          \
                                                  ((G) * 3 + j) * 32);         \
    }

#define GRP(G, POFS)                                                           \
    {                                                                          \
        _Pragma("unroll") for (int j = 0; j < 3; ++j) {                        \
            const int khw = (G) * 3 + j;                                       \
            const int kh = khw / 3, kw = khw - kh * 3;                         \
            _Pragma("unroll") for (int nt = 0; nt < 7; ++nt) {                 \
                int p = pb[nt] + kh * TPC + kw;                                \
                int boff = (p << 6) + (((lq ^ (p >> 1)) & 3) << 4);            \
                bf16x8 bfr = *(const bf16x8*)((char*)Bs + (POFS) + boff);      \
                _Pragma("unroll") for (int mt = 0; mt < 4; ++mt)               \
                    acc[mt][nt] = __builtin_amdgcn_mfma_f32_16x16x32_bf16(     \
                        af[j * 4 + mt], bfr, acc[mt][nt], 0, 0, 0);            \
            }                                                                  \
        }                                                                      \
    }

    STAGE(0, 0);                 // chunk 0 -> buf0
    LOADA(0, 0);                 // chunk 0, khw 0-2
    for (int it = 0; it < 4; ++it) {
        // ---- chunk 2*it (buf0) ----
        __syncthreads();         // drains staging of this chunk
        STAGE(32, BUFB);         // chunk 2it+1 -> buf1 (hidden behind compute)
        GRP(0, 0);
        LOADA(0, 1);  GRP(1, 0);
        LOADA(0, 2);  GRP(2, 0);
        LOADA(288, 0);           // next chunk's khw 0-2 (pre-barrier)
        // ---- chunk 2*it+1 (buf1) ----
        __syncthreads();
        if (it < 3) STAGE(64, 0);        // chunk 2it+2 -> buf0
        GRP(0, BUFB);
        LOADA(288, 1); GRP(1, BUFB);
        LOADA(288, 2); GRP(2, BUFB);
        if (it < 3) {
#pragma unroll
            for (int mt = 0; mt < 4; ++mt) aptr[mt] += 576;
#pragma unroll
            for (int i = 0; i < 3; ++i) gsrc[i] += 64;
            LOADA(0, 0);                 // chunk 2it+2, khw 0-2
        }
    }
#undef STAGE
#undef LOADA
#undef GRP

    // Epilogue: D row = lq*4 + r (o), col = lm (n)
#pragma unroll
    for (int mt = 0; mt < 4; ++mt) {
        int o = mb * 256 + w * 64 + mt * 16 + lq * 4;
#pragma unroll
        for (int nt = 0; nt < 7; ++nt) {
            int n = nt * 16 + lm;
            int ny = n / NX, nx = n - (n / NX) * NX;
            size_t base =
                (((size_t)b * OO + o) * HH + (y0 + ny)) * WW + (x0 + nx);
#pragma unroll
            for (int r = 0; r < 4; ++r)
                out[base + (size_t)r * HH * WW] = acc[mt][nt][r];
        }
    }
}

extern "C" void kernel_launch(void* const* d_in, const int* in_sizes, int n_in,
                              void* d_out, int out_size, void* d_ws, size_t ws_size,
                              hipStream_t stream) {
    const float* x   = (const float*)d_in[0];
    const void*  pos = d_in[1];
    const void*  neg = d_in[2];
    float* out = (float*)d_out;

    unsigned int* flag = (unsigned int*)d_ws;
    unsigned short* wt = (unsigned short*)((char*)d_ws + WT_OFF);
    unsigned short* xpad = (unsigned short*)((char*)d_ws + XP_OFF);

    detect_bool_width<<<1, 256, 0, stream>>>((const unsigned int*)pos, flag);
    decode_w<<<288, 256, 0, stream>>>(pos, neg, flag, wt);
    pad_x<<<BB * XR, 256, 0, stream>>>(x, xpad);
    conv_mfma<<<dim3(1792), 256, 0, stream>>>(xpad, wt, out);
}

// Round 2
// 716.766 us; speedup vs baseline: 1.1432x; 1.1432x over previous
//
#include <hip/hip_runtime.h>
#include <hip/hip_bf16.h>

#define BB 32
#define CC 256
#define HH 56
#define WW 56
#define OO 512
#define CKK 2304

// padded x, NHWC bf16: [b][pix = y*58 + x][c], y,x in [0,58)
#define XR 58
#define XC 58
#define XPIX (XR * XC)        // 3364

// GEMM tiling: M-tile 256 (o), N-tile 112 = 4 y-rows x 28 x-cols
#define NY 4
#define NX 28
#define NTILE 112
#define TPC 30                // tile pixel cols (NX+2)
#define TPIX 180              // 6 rows * 30 cols
#define PSTR 80               // LDS pixel stride (64B data + 16B pad): bank
                              // slot = (5p+lq)%8 -> 2-way max (conflict-free)
#define BUFB 16384            // LDS buffer stride (bytes); used 180*80=14400

typedef __bf16 bf16x8 __attribute__((ext_vector_type(8)));
typedef float  f32x4  __attribute__((ext_vector_type(4)));

#define WT_OFF 4096
#define XP_OFF (WT_OFF + (size_t)OO * CKK * 2)   // 2.36 MB of weights

// ---------------------------------------------------------------------------
// Detect 1-byte vs 4-byte bools (u32 words > 1 => byte bools).
// ---------------------------------------------------------------------------
__global__ void detect_bool_width(const unsigned int* __restrict__ pos,
                                  unsigned int* __restrict__ flag) {
    unsigned int v = 0;
    for (int i = threadIdx.x; i < 16384; i += 256) v |= pos[i];
    __shared__ unsigned int red;
    if (threadIdx.x == 0) red = 0u;
    __syncthreads();
    if (v > 1u) atomicOr(&red, 1u);
    __syncthreads();
    if (threadIdx.x == 0) *flag = red;
}

// ---------------------------------------------------------------------------
// Decode ternary weights to bf16, transposed to w[o][k'] with
// k' = (c>>5)*288 + (kh*3+kw)*32 + (c&31)  (c-chunk-major, khw, c-in-chunk).
// ---------------------------------------------------------------------------
__global__ __launch_bounds__(256) void decode_w(
    const void* __restrict__ posv, const void* __restrict__ negv,
    const unsigned int* __restrict__ flag,
    unsigned short* __restrict__ wt) {
    __shared__ unsigned short lds[64][65];
    int blk = blockIdx.x;
    int ot  = blk & 7;
    int khw = (blk >> 3) % 9;
    int ct  = blk / 72;
    int o0 = ot * 64, c0 = ct * 64;
    int t = threadIdx.x;
    int o_l = t & 63, row4 = t >> 6;
    bool bytes = (*flag != 0u);
#pragma unroll
    for (int r = 0; r < 16; ++r) {
        int c_l = row4 + r * 4;
        long k = (long)(c0 + c_l) * 9 + khw;     // input k = c*9 + kh*3 + kw
        long idx = k * OO + o0 + o_l;
        int p, q;
        if (bytes) { p = ((const unsigned char*)posv)[idx];
                     q = ((const unsigned char*)negv)[idx]; }
        else       { p = ((const int*)posv)[idx];
                     q = ((const int*)negv)[idx]; }
        lds[c_l][o_l] = p ? 0x3F80u : (q ? 0xBF80u : 0u);
    }
    __syncthreads();
#pragma unroll
    for (int r = 0; r < 16; ++r) {
        int o_r = row4 + r * 4;
        int c = c0 + (t & 63);
        wt[(size_t)(o0 + o_r) * CKK + (c >> 5) * 288 + khw * 32 + (c & 31)] =
            lds[t & 63][o_r];
    }
}

// ---------------------------------------------------------------------------
// Pad + convert + transpose x to NHWC bf16: xp[b][y*58+x][c].
// One block per (b, y) output row; LDS transpose per 64-c chunk.
// ---------------------------------------------------------------------------
__global__ __launch_bounds__(256) void pad_x(const float* __restrict__ x,
                                             unsigned short* __restrict__ xp) {
    int blk = blockIdx.x;                 // 32*58
    int b = blk / XR, y = blk - b * XR;
    int t = threadIdx.x;
    unsigned short* rowp = xp + ((size_t)b * XPIX + (size_t)y * XC) * CC;
    if (y == 0 || y == XR - 1) {
        uint4 z = {0, 0, 0, 0};
        for (int i = t; i < XC * CC / 8; i += 256) ((uint4*)rowp)[i] = z;
        return;
    }
    __shared__ float lds[WW][65];
    for (int cb = 0; cb < 4; ++cb) {
        if (cb) __syncthreads();
#pragma unroll
        for (int i = 0; i < 14; ++i) {    // 3584 = 64 c * 56 x
            int idx = i * 256 + t;
            int cl = idx / WW, xx = idx - cl * WW;
            lds[xx][cl] =
                x[(((size_t)b * CC + cb * 64 + cl) * HH + (y - 1)) * WW + xx];
        }
        __syncthreads();
#pragma unroll
        for (int i = 0; i < 15; ++i) {    // 3712 = 58 x * 64 c
            int idx = i * 256 + t;
            if (idx < XC * 64) {
                int xx = idx >> 6, cl = idx & 63;
                float v = (xx == 0 || xx == XC - 1) ? 0.f : lds[xx - 1][cl];
                __hip_bfloat16 h = __float2bfloat16(v);
                rowp[(size_t)xx * CC + cb * 64 + cl] = *(unsigned short*)&h;
            }
        }
    }
}

// ---------------------------------------------------------------------------
// Implicit-GEMM conv, bf16 MFMA, c-chunk-outer K-loop.
//   Per chunk: stage 180 pix x 32 c tile (global->reg->ds_write, 80B pixel
//   stride so B-frag ds_read_b128 is bank-conflict-free), double-buffered;
//   then 9 khw K-steps x 28 MFMAs per wave from LDS. 1 barrier / chunk.
// Grid 1792 = 896 n-blocks x 2 m-blocks (m swizzled onto same XCD).
// Global staging loads stay linear/coalesced; all ds_read addresses are
// one precomputed VGPR + compile-time immediate (register-cap discipline).
// ---------------------------------------------------------------------------
__global__ __launch_bounds__(256, 2) void conv_mfma(
    const unsigned short* __restrict__ xp,
    const unsigned short* __restrict__ wt,
    float* __restrict__ out) {
    __shared__ __align__(1024) unsigned short Bs[2 * BUFB / 2];

    int t = threadIdx.x;
    int w = t >> 6, lane = t & 63, lm = lane & 15, lq = lane >> 4;

    int bx = blockIdx.x;
    int mb = (bx >> 3) & 1;                       // m innermost on same XCD
    int gn = ((bx >> 4) << 3) | (bx & 7);         // 0..895
    int b = gn / 28;
    int rem = gn - b * 28;
    int y0 = (rem >> 1) << 2;                     // 0..52
    int x0 = (rem & 1) * NX;                      // 0 or 28

    // B-fragment LDS byte offsets per nt (kh=kw=0 position), padded stride
    int bofs[7];
#pragma unroll
    for (int nt = 0; nt < 7; ++nt) {
        int n = nt * 16 + lm;
        int ny = n / NX, nx = n - (n / NX) * NX;
        bofs[nt] = (ny * TPC + nx) * PSTR + lq * 16;
    }

    // Staging: 720 16-B units; 3 per thread, u = u0 + 64*i, u0 = w*192+lane.
    // Global source linear (pix = u>>2, quad = u&3); LDS dest padded:
    // wadr = pix*80 + quad*16 (unit step 64 -> pix step 16 -> +1280 B).
    int u0 = w * 192 + lane;                       // 0..639 (i=0 always valid)
    const unsigned short* gsrc[3];
#pragma unroll
    for (int i = 0; i < 3; ++i) {
        int u = u0 + 64 * i;
        int pix = u >> 2, q = u & 3;
        int py = pix / TPC, px = pix - py * TPC;
        gsrc[i] = xp + ((size_t)b * XPIX + (y0 + py) * XC + (x0 + px)) * CC +
                  q * 8;
    }
    int wadr0 = (u0 >> 2) * PSTR + (u0 & 3) * 16;

    const unsigned short* aptr[4];
#pragma unroll
    for (int mt = 0; mt < 4; ++mt)
        aptr[mt] = wt + (size_t)(mb * 256 + w * 64 + mt * 16 + lm) * CKK + lq * 8;

    f32x4 acc[4][7];
#pragma unroll
    for (int i = 0; i < 4; ++i)
#pragma unroll
        for (int j = 0; j < 7; ++j) acc[i][j] = (f32x4){0.f, 0.f, 0.f, 0.f};

    bf16x8 af[12];
    bf16x8 s0, s1, s2;

#define GLOAD01(CHOFF)                                                         \
    {                                                                          \
        s0 = *(const bf16x8*)(gsrc[0] + (CHOFF));                              \
        if (u0 < 656) s1 = *(const bf16x8*)(gsrc[1] + (CHOFF));                \
    }
#define GLOAD2(CHOFF)                                                          \
    {                                                                          \
        if (u0 < 592) s2 = *(const bf16x8*)(gsrc[2] + (CHOFF));                \
    }
#define DSW01(POFS)                                                            \
    {                                                                          \
        *(bf16x8*)((char*)Bs + (POFS) + wadr0) = s0;                           \
        if (u0 < 656) *(bf16x8*)((char*)Bs + (POFS) + wadr0 + 1280) = s1;      \
    }
#define DSW2(POFS)                                                             \
    {                                                                          \
        if (u0 < 592) *(bf16x8*)((char*)Bs + (POFS) + wadr0 + 2560) = s2;      \
    }

#define LOADA(CHEL, G)                                                         \
    {                                                                          \
        _Pragma("unroll") for (int j = 0; j < 3; ++j)                          \
            _Pragma("unroll") for (int mt = 0; mt < 4; ++mt)                   \
                af[j * 4 + mt] = *(const bf16x8*)(aptr[mt] + (CHEL) +          \
                                                  ((G) * 3 + j) * 32);         \
    }

#define GRP(G, POFS)                                                           \
    {                                                                          \
        _Pragma("unroll") for (int j = 0; j < 3; ++j) {                        \
            const int khw = (G) * 3 + j;                                       \
            const int kh = khw / 3, kw = khw - kh * 3;                         \
            _Pragma("unroll") for (int nt = 0; nt < 7; ++nt) {                 \
                bf16x8 bfr = *(const bf16x8*)((char*)Bs + (POFS) +             \
                                              (kh * TPC + kw) * PSTR +         \
                                              bofs[nt]);                       \
                _Pragma("unroll") for (int mt = 0; mt < 4; ++mt)               \
                    acc[mt][nt] = __builtin_amdgcn_mfma_f32_16x16x32_bf16(     \
                        af[j * 4 + mt], bfr, acc[mt][nt], 0, 0, 0);            \
            }                                                                  \
        }                                                                      \
    }

    // Prologue: stage chunk 0 into buf0 (published by first barrier).
    GLOAD01(0); GLOAD2(0);
    DSW01(0);   DSW2(0);
    LOADA(0, 0);                 // chunk 0, khw 0-2
    for (int it = 0; it < 4; ++it) {
        // ---- chunk 2*it (buf0) ----
        __syncthreads();         // buf0 written by all waves
        GLOAD01(32);             // chunk 2it+1 loads (latency under GRPs)
        GRP(0, 0);
        LOADA(0, 1); GLOAD2(32);
        GRP(1, 0);
        DSW01(BUFB);             // chunk 2it+1 -> buf1 (buf1 reads done pre-barrier)
        LOADA(0, 2); GRP(2, 0);
        DSW2(BUFB);
        LOADA(288, 0);           // next chunk's khw 0-2 (pre-barrier)
        // ---- chunk 2*it+1 (buf1) ----
        __syncthreads();
        if (it < 3) GLOAD01(64);
        GRP(0, BUFB);
        LOADA(288, 1);
        if (it < 3) GLOAD2(64);
        GRP(1, BUFB);
        if (it < 3) DSW01(0);    // chunk 2it+2 -> buf0
        LOADA(288, 2); GRP(2, BUFB);
        if (it < 3) {
            DSW2(0);
#pragma unroll
            for (int mt = 0; mt < 4; ++mt) aptr[mt] += 576;
#pragma unroll
            for (int i = 0; i < 3; ++i) gsrc[i] += 64;
            LOADA(0, 0);                 // chunk 2it+2, khw 0-2
        }
    }
#undef GLOAD01
#undef GLOAD2
#undef DSW01
#undef DSW2
#undef LOADA
#undef GRP

    // Epilogue: D row = lq*4 + r (o), col = lm (n)
#pragma unroll
    for (int mt = 0; mt < 4; ++mt) {
        int o = mb * 256 + w * 64 + mt * 16 + lq * 4;
#pragma unroll
        for (int nt = 0; nt < 7; ++nt) {
            int n = nt * 16 + lm;
            int ny = n / NX, nx = n - (n / NX) * NX;
            size_t base =
                (((size_t)b * OO + o) * HH + (y0 + ny)) * WW + (x0 + nx);
#pragma unroll
            for (int r = 0; r < 4; ++r)
                out[base + (size_t)r * HH * WW] = acc[mt][nt][r];
        }
    }
}

extern "C" void kernel_launch(void* const* d_in, const int* in_sizes, int n_in,
                              void* d_out, int out_size, void* d_ws, size_t ws_size,
                              hipStream_t stream) {
    const float* x   = (const float*)d_in[0];
    const void*  pos = d_in[1];
    const void*  neg = d_in[2];
    float* out = (float*)d_out;

    unsigned int* flag = (unsigned int*)d_ws;
    unsigned short* wt = (unsigned short*)((char*)d_ws + WT_OFF);
    unsigned short* xpad = (unsigned short*)((char*)d_ws + XP_OFF);

    detect_bool_width<<<1, 256, 0, stream>>>((const unsigned int*)pos, flag);
    decode_w<<<288, 256, 0, stream>>>(pos, neg, flag, wt);
    pad_x<<<BB * XR, 256, 0, stream>>>(x, xpad);
    conv_mfma<<<dim3(1792), 256, 0, stream>>>(xpad, wt, out);
}

// Round 3
// 709.177 us; speedup vs baseline: 1.1554x; 1.0107x over previous
//
#include <hip/hip_runtime.h>
#include <hip/hip_bf16.h>

#define BB 32
#define CC 256
#define HH 56
#define WW 56
#define OO 512
#define CKK 2304

// padded x, NHWC bf16: [b][pix = y*58 + x][c], y,x in [0,58)
#define XR 58
#define XC 58
#define XPIX (XR * XC)        // 3364

// GEMM tiling: M-tile 256 (o), N-tile 112 = 4 y-rows x 28 x-cols
#define NY 4
#define NX 28
#define NTILE 112
#define TPC 30                // tile pixel cols (NX+2)
#define TPIX 180              // 6 rows * 30 cols
#define BUFB 16384            // LDS buffer stride (bytes); used 11,520

typedef __bf16 bf16x8 __attribute__((ext_vector_type(8)));
typedef float  f32x4  __attribute__((ext_vector_type(4)));

#define WT_OFF 4096
#define XP_OFF (WT_OFF + (size_t)OO * CKK * 2)   // 2.36 MB of weights

// ---------------------------------------------------------------------------
// Detect 1-byte vs 4-byte bools (u32 words > 1 => byte bools).
// ---------------------------------------------------------------------------
__global__ void detect_bool_width(const unsigned int* __restrict__ pos,
                                  unsigned int* __restrict__ flag) {
    unsigned int v = 0;
    for (int i = threadIdx.x; i < 16384; i += 256) v |= pos[i];
    __shared__ unsigned int red;
    if (threadIdx.x == 0) red = 0u;
    __syncthreads();
    if (v > 1u) atomicOr(&red, 1u);
    __syncthreads();
    if (threadIdx.x == 0) *flag = red;
}

// ---------------------------------------------------------------------------
// Decode ternary weights to bf16, transposed to w[o][k'] with
// k' = (c>>5)*288 + (kh*3+kw)*32 + (c&31)  (c-chunk-major, khw, c-in-chunk).
// ---------------------------------------------------------------------------
__global__ __launch_bounds__(256) void decode_w(
    const void* __restrict__ posv, const void* __restrict__ negv,
    const unsigned int* __restrict__ flag,
    unsigned short* __restrict__ wt) {
    __shared__ unsigned short lds[64][65];
    int blk = blockIdx.x;
    int ot  = blk & 7;
    int khw = (blk >> 3) % 9;
    int ct  = blk / 72;
    int o0 = ot * 64, c0 = ct * 64;
    int t = threadIdx.x;
    int o_l = t & 63, row4 = t >> 6;
    bool bytes = (*flag != 0u);
#pragma unroll
    for (int r = 0; r < 16; ++r) {
        int c_l = row4 + r * 4;
        long k = (long)(c0 + c_l) * 9 + khw;     // input k = c*9 + kh*3 + kw
        long idx = k * OO + o0 + o_l;
        int p, q;
        if (bytes) { p = ((const unsigned char*)posv)[idx];
                     q = ((const unsigned char*)negv)[idx]; }
        else       { p = ((const int*)posv)[idx];
                     q = ((const int*)negv)[idx]; }
        lds[c_l][o_l] = p ? 0x3F80u : (q ? 0xBF80u : 0u);
    }
    __syncthreads();
#pragma unroll
    for (int r = 0; r < 16; ++r) {
        int o_r = row4 + r * 4;
        int c = c0 + (t & 63);
        wt[(size_t)(o0 + o_r) * CKK + (c >> 5) * 288 + khw * 32 + (c & 31)] =
            lds[t & 63][o_r];
    }
}

// ---------------------------------------------------------------------------
// Pad + convert + transpose x to NHWC bf16: xp[b][y*58+x][c].
// One block per (b, y) output row; LDS transpose per 64-c chunk.
// ---------------------------------------------------------------------------
__global__ __launch_bounds__(256) void pad_x(const float* __restrict__ x,
                                             unsigned short* __restrict__ xp) {
    int blk = blockIdx.x;                 // 32*58
    int b = blk / XR, y = blk - b * XR;
    int t = threadIdx.x;
    unsigned short* rowp = xp + ((size_t)b * XPIX + (size_t)y * XC) * CC;
    if (y == 0 || y == XR - 1) {
        uint4 z = {0, 0, 0, 0};
        for (int i = t; i < XC * CC / 8; i += 256) ((uint4*)rowp)[i] = z;
        return;
    }
    __shared__ float lds[WW][65];
    for (int cb = 0; cb < 4; ++cb) {
        if (cb) __syncthreads();
#pragma unroll
        for (int i = 0; i < 14; ++i) {    // 3584 = 64 c * 56 x
            int idx = i * 256 + t;
            int cl = idx / WW, xx = idx - cl * WW;
            lds[xx][cl] =
                x[(((size_t)b * CC + cb * 64 + cl) * HH + (y - 1)) * WW + xx];
        }
        __syncthreads();
#pragma unroll
        for (int i = 0; i < 15; ++i) {    // 3712 = 58 x * 64 c
            int idx = i * 256 + t;
            if (idx < XC * 64) {
                int xx = idx >> 6, cl = idx & 63;
                float v = (xx == 0 || xx == XC - 1) ? 0.f : lds[xx - 1][cl];
                __hip_bfloat16 h = __float2bfloat16(v);
                rowp[(size_t)xx * CC + cb * 64 + cl] = *(unsigned short*)&h;
            }
        }
    }
}

// ---------------------------------------------------------------------------
// Implicit-GEMM conv, bf16 MFMA, c-chunk-outer K-loop.
//   Per chunk: stage 180 pix x 32 c tile via global_load_lds (double-buffered),
//   then 9 khw K-steps x 28 MFMAs per wave from LDS. 1 barrier / chunk.
// A-weights are loaded j-granularly into ping-pong buffers afA/afB (4 regs
// each): while GRPJ(j) consumes one buffer, the 4 loads for j+1 fill the
// other -- no WAR hazard, so the L2 A-stream overlaps MFMA issue.
// Grid 1792 = 896 n-blocks x 2 m-blocks (m swizzled onto same XCD).
// ---------------------------------------------------------------------------
__global__ __launch_bounds__(256, 2) void conv_mfma(
    const unsigned short* __restrict__ xp,
    const unsigned short* __restrict__ wt,
    float* __restrict__ out) {
    __shared__ __align__(1024) unsigned short Bs[2 * BUFB / 2];

    int t = threadIdx.x;
    int w = t >> 6, lane = t & 63, lm = lane & 15, lq = lane >> 4;

    int bx = blockIdx.x;
    int mb = (bx >> 3) & 1;                       // m innermost on same XCD
    int gn = ((bx >> 4) << 3) | (bx & 7);         // 0..895
    int b = gn / 28;
    int rem = gn - b * 28;
    int y0 = (rem >> 1) << 2;                     // 0..52
    int x0 = (rem & 1) * NX;                      // 0 or 28

    // B-fragment LDS byte offsets per nt (kh=kw=0 position)
    int bofs[7];
#pragma unroll
    for (int nt = 0; nt < 7; ++nt) {
        int n = nt * 16 + lm;
        int ny = n / NX, nx = n - (n / NX) * NX;
        bofs[nt] = (ny * TPC + nx) * 64 + lq * 16;
    }

    // Staging: 720 16-B units; 3 segments/wave, u = (w*3+i)*64 + lane
    const unsigned short* gsrc[3];
    int useg[3];
#pragma unroll
    for (int i = 0; i < 3; ++i) {
        int u = (w * 3 + i) * 64 + lane;
        useg[i] = u;
        int pix = u >> 2, quad = u & 3;
        int py = pix / TPC, px = pix - py * TPC;
        gsrc[i] = xp + ((size_t)b * XPIX + (y0 + py) * XC + (x0 + px)) * CC +
                  quad * 8;
    }
    int ldsseg = (w * 3) * 1024;

    const unsigned short* aptr[4];
#pragma unroll
    for (int mt = 0; mt < 4; ++mt)
        aptr[mt] = wt + (size_t)(mb * 256 + w * 64 + mt * 16 + lm) * CKK + lq * 8;

    f32x4 acc[4][7];
#pragma unroll
    for (int i = 0; i < 4; ++i)
#pragma unroll
        for (int j = 0; j < 7; ++j) acc[i][j] = (f32x4){0.f, 0.f, 0.f, 0.f};

    bf16x8 afA[4], afB[4];

#define STAGE(CHOFF, POFS)                                                     \
    {                                                                          \
        _Pragma("unroll") for (int i = 0; i < 3; ++i) {                        \
            if (useg[i] < TPIX * 4)                                            \
                __builtin_amdgcn_global_load_lds(                              \
                    (const __attribute__((address_space(1))) void*)(gsrc[i] +  \
                                                                    (CHOFF)),  \
                    (__attribute__((address_space(3))) void*)((char*)Bs +      \
                                                              (POFS) + ldsseg +\
                                                              i * 1024),       \
                    16, 0, 0);                                                 \
        }                                                                      \
    }

#define LOADJ(BUF, CHEL, J)                                                    \
    {                                                                          \
        _Pragma("unroll") for (int mt = 0; mt < 4; ++mt)                       \
            BUF[mt] = *(const bf16x8*)(aptr[mt] + (CHEL) + (J) * 32);          \
    }

#define GRPJ(J, POFS, BUF)                                                     \
    {                                                                          \
        const int kh = (J) / 3, kw = (J) - kh * 3;                             \
        _Pragma("unroll") for (int nt = 0; nt < 7; ++nt) {                     \
            bf16x8 bfr = *(const bf16x8*)((char*)Bs + (POFS) +                 \
                                          (kh * TPC + kw) * 64 + bofs[nt]);    \
            _Pragma("unroll") for (int mt = 0; mt < 4; ++mt)                   \
                acc[mt][nt] = __builtin_amdgcn_mfma_f32_16x16x32_bf16(         \
                    BUF[mt], bfr, acc[mt][nt], 0, 0, 0);                       \
        }                                                                      \
    }

    STAGE(0, 0);                 // chunk 0 -> buf0
    LOADJ(afA, 0, 0);            // chunk 0, j0
    for (int it = 0; it < 4; ++it) {
        // ---- chunk 2*it (buf0) ----
        __syncthreads();         // drains staging of this chunk
        STAGE(32, BUFB);         // chunk 2it+1 -> buf1 (hidden behind compute)
        LOADJ(afB, 0, 1);   GRPJ(0, 0, afA);
        LOADJ(afA, 0, 2);   GRPJ(1, 0, afB);
        LOADJ(afB, 0, 3);   GRPJ(2, 0, afA);
        LOADJ(afA, 0, 4);   GRPJ(3, 0, afB);
        LOADJ(afB, 0, 5);   GRPJ(4, 0, afA);
        LOADJ(afA, 0, 6);   GRPJ(5, 0, afB);
        LOADJ(afB, 0, 7);   GRPJ(6, 0, afA);
        LOADJ(afA, 0, 8);   GRPJ(7, 0, afB);
        LOADJ(afB, 288, 0); GRPJ(8, 0, afA);   // preload odd-chunk j0
        // ---- chunk 2*it+1 (buf1) ----
        __syncthreads();
        if (it < 3) STAGE(64, 0);        // chunk 2it+2 -> buf0
        LOADJ(afA, 288, 1); GRPJ(0, BUFB, afB);
        LOADJ(afB, 288, 2); GRPJ(1, BUFB, afA);
        LOADJ(afA, 288, 3); GRPJ(2, BUFB, afB);
        LOADJ(afB, 288, 4); GRPJ(3, BUFB, afA);
        LOADJ(afA, 288, 5); GRPJ(4, BUFB, afB);
        LOADJ(afB, 288, 6); GRPJ(5, BUFB, afA);
        LOADJ(afA, 288, 7); GRPJ(6, BUFB, afB);
        LOADJ(afB, 288, 8); GRPJ(7, BUFB, afA);
        if (it < 3) {
            LOADJ(afA, 576, 0);          // preload next even chunk j0
            GRPJ(8, BUFB, afB);
#pragma unroll
            for (int mt = 0; mt < 4; ++mt) aptr[mt] += 576;
#pragma unroll
            for (int i = 0; i < 3; ++i) gsrc[i] += 64;
        } else {
            GRPJ(8, BUFB, afB);
        }
    }
#undef STAGE
#undef LOADJ
#undef GRPJ

    // Epilogue: D row = lq*4 + r (o), col = lm (n)
#pragma unroll
    for (int mt = 0; mt < 4; ++mt) {
        int o = mb * 256 + w * 64 + mt * 16 + lq * 4;
#pragma unroll
        for (int nt = 0; nt < 7; ++nt) {
            int n = nt * 16 + lm;
            int ny = n / NX, nx = n - (n / NX) * NX;
            size_t base =
                (((size_t)b * OO + o) * HH + (y0 + ny)) * WW + (x0 + nx);
#pragma unroll
            for (int r = 0; r < 4; ++r)
                out[base + (size_t)r * HH * WW] = acc[mt][nt][r];
        }
    }
}

extern "C" void kernel_launch(void* const* d_in, const int* in_sizes, int n_in,
                              void* d_out, int out_size, void* d_ws, size_t ws_size,
                              hipStream_t stream) {
    const float* x   = (const float*)d_in[0];
    const void*  pos = d_in[1];
    const void*  neg = d_in[2];
    float* out = (float*)d_out;

    unsigned int* flag = (unsigned int*)d_ws;
    unsigned short* wt = (unsigned short*)((char*)d_ws + WT_OFF);
    unsigned short* xpad = (unsigned short*)((char*)d_ws + XP_OFF);

    detect_bool_width<<<1, 256, 0, stream>>>((const unsigned int*)pos, flag);
    decode_w<<<288, 256, 0, stream>>>(pos, neg, flag, wt);
    pad_x<<<BB * XR, 256, 0, stream>>>(x, xpad);
    conv_mfma<<<dim3(1792), 256, 0, stream>>>(xpad, wt, out);
}